// Round 3
// baseline (198.796 us; speedup 1.0000x reference)
//
#include <hip/hip_runtime.h>
#include <math.h>

// Problem constants (match reference config)
#define GPB    8                 // k-vectors per reciprocal block
#define GTOT   729               // (2*NMAX+1)^3, NMAX=4
#define GMAX   46                // ceil(364/8): worst-case active half-sphere k's / GPB
#define KMAX   (GMAX*GPB)        // compacted k slots per system (padded)
#define APB    80                // atoms per real block: must divide N, multiple of 4
#define STRIDE_LEG 344           // legacy fallback partial stride

__device__ __forceinline__ float wave_reduce(float v) {
    #pragma unroll
    for (int off = 32; off > 0; off >>= 1) v += __shfl_down(v, off, 64);
    return v;
}

// Abramowitz & Stegun 7.1.26: erfc(x) for x>=0, |abs err| <= 1.5e-7.
__device__ __forceinline__ float fast_erfc(float x) {
    float t = __builtin_amdgcn_rcpf(fmaf(0.3275911f, x, 1.0f));
    float p = fmaf(1.061405429f, t, -1.453152027f);
    p = fmaf(p, t, 1.421413741f);
    p = fmaf(p, t, -0.284496736f);
    p = fmaf(p, t, 0.254829592f);
    return p * t * __expf(-x * x);
}

// ---------- prologue: pack pq + build compacted k-vectors + zero counters ---
__global__ __launch_bounds__(256)
void prologue(const float* __restrict__ pos, const float* __restrict__ chg,
              float4* __restrict__ pq, const float* __restrict__ cell,
              float4* __restrict__ kcomp, int* __restrict__ kcnt,
              int* __restrict__ done, int T, int PB)
{
    int blk = blockIdx.x;
    if (blk < PB) {
        int t = blk * 256 + threadIdx.x;
        if (t < T)
            pq[t] = make_float4(pos[3*t], pos[3*t+1], pos[3*t+2], chg[t]);
        return;
    }
    // one system per block; wave 0 does the compaction scan
    int b = blk - PB;
    if (threadIdx.x == 64) done[b] = 0;
    if (threadIdx.x >= 64) return;

    const float TWO_PI = 6.283185307179586f;
    const float INV4A2 = 2.7777777777f;          // 1/(4*ALPHA^2)
    const float KC2    = 1.0f;
    int lane = threadIdx.x;

    const float* C = cell + 9 * b;
    float m00=C[0], m01=C[1], m02=C[2];
    float m10=C[3], m11=C[4], m12=C[5];
    float m20=C[6], m21=C[7], m22=C[8];
    float a00 = m11*m22 - m12*m21;
    float a01 = m02*m21 - m01*m22;
    float a02 = m01*m12 - m02*m11;
    float a10 = m12*m20 - m10*m22;
    float a11 = m00*m22 - m02*m20;
    float a12 = m02*m10 - m00*m12;
    float a20 = m10*m21 - m11*m20;
    float a21 = m01*m20 - m00*m21;
    float a22 = m00*m11 - m01*m10;
    float det = m00*a00 + m01*a10 + m02*a20;
    float invdet = 1.0f / det;
    float vol = fabsf(det);

    int cnt = 0;
    for (int base = 0; base < GTOT; base += 64) {
        int g = base + lane;
        float kx = 0.f, ky = 0.f, kz = 0.f, cf = 0.f;
        if (g < GTOT) {
            int ix = g / 81, rem = g - ix * 81;
            int iy = rem / 9, iz = rem - iy * 9;
            int nx = ix - 4, ny = iy - 4, nz = iz - 4;
            bool pos_half = (nx > 0) || (nx == 0 && (ny > 0 || (ny == 0 && nz > 0)));
            if (pos_half) {
                float fx = (float)nx, fy = (float)ny, fz = (float)nz;
                kx = TWO_PI * invdet * (fx*a00 + fy*a01 + fz*a02);
                ky = TWO_PI * invdet * (fx*a10 + fy*a11 + fz*a12);
                kz = TWO_PI * invdet * (fx*a20 + fy*a21 + fz*a22);
                float k2 = kx*kx + ky*ky + kz*kz;
                if (k2 > 1e-10f && k2 <= KC2) {
                    // 2 * [4*pi*exp(-k2/4a^2)/k2] / (2*vol)  (half-sphere doubling)
                    cf = 12.566370614359172f * __expf(-k2 * INV4A2) / (k2 * vol);
                }
            }
        }
        bool act = (cf != 0.f);
        unsigned long long m = __ballot(act);
        if (act) {
            int off = __popcll(m & ((1ull << lane) - 1ull));
            kcomp[b * KMAX + cnt + off] = make_float4(kx, ky, kz, cf);
        }
        cnt += (int)__popcll(m);
    }
    int padded = ((cnt + GPB - 1) / GPB) * GPB;
    if (lane < padded - cnt)
        kcomp[b * KMAX + cnt + lane] = make_float4(0.f, 0.f, 0.f, 0.f);
    if (lane == 0) kcnt[b] = padded / GPB;
}

// ---------- fused main kernel: recip + real + merged deterministic reduce ---
// KK = compile-time neighbor count (0 -> runtime K)
template <int KK>
__global__ __launch_bounds__(256)
void ewald_main(const float4* __restrict__ pq,
                const float*  __restrict__ cell,
                const int*    __restrict__ nm,
                const int*    __restrict__ shifts,
                const int*    __restrict__ nnb,
                const float4* __restrict__ kcomp,
                const int*    __restrict__ kcnt,
                float* __restrict__ partial,   // [Bn][stride]
                int*   __restrict__ done,      // [Bn]
                float* __restrict__ out,       // [Bn]
                int T, int N, int K, int Bn, int CB, int RPS)
{
    __shared__ float4 skv[GPB];
    __shared__ float  redA[4][GPB];
    __shared__ float  redB[4][GPB];
    __shared__ float  redr[4];
    __shared__ float  redf[4];
    __shared__ int    sflag;

    const float ALPHA       = 0.3f;
    const float INV_SQRT_PI = 0.5641895835477563f;

    int blk  = blockIdx.x;
    int tid  = threadIdx.x;
    int lane = tid & 63;
    int w    = tid >> 6;
    int stride = RPS + GMAX;

    float pval = 0.f;     // block's partial (valid on tid 0)
    int sys, slot;

    if (blk < CB) {
        // ======================= reciprocal space ==========================
        int b   = blk / GMAX;
        int grp = blk - b * GMAX;
        sys  = b;
        slot = b * stride + RPS + grp;
        int ng = kcnt[b];

        if (grp < ng) {
            if (tid < GPB)
                skv[tid] = kcomp[b * KMAX + grp * GPB + tid];
            __syncthreads();

            float kvx[GPB], kvy[GPB], kvz[GPB];
            #pragma unroll
            for (int gi = 0; gi < GPB; ++gi) {
                float4 v = skv[gi];
                kvx[gi] = v.x; kvy[gi] = v.y; kvz[gi] = v.z;
            }

            float Sre[GPB], Sim[GPB];
            #pragma unroll
            for (int gi = 0; gi < GPB; ++gi) { Sre[gi] = 0.f; Sim[gi] = 0.f; }

            const float4* pb = pq + (size_t)b * N;
            int a = tid;
            for (; a + 256 < N; a += 512) {          // 2 atoms / iteration
                float4 v0 = pb[a];
                float4 v1 = pb[a + 256];
                #pragma unroll
                for (int gi = 0; gi < GPB; ++gi) {
                    float ph0 = fmaf(v0.x, kvx[gi], fmaf(v0.y, kvy[gi], v0.z * kvz[gi]));
                    float ph1 = fmaf(v1.x, kvx[gi], fmaf(v1.y, kvy[gi], v1.z * kvz[gi]));
                    float s0, c0, s1, c1;
                    __sincosf(ph0, &s0, &c0);
                    __sincosf(ph1, &s1, &c1);
                    Sre[gi] = fmaf(v0.w, c0, Sre[gi]);
                    Sim[gi] = fmaf(v0.w, s0, Sim[gi]);
                    Sre[gi] = fmaf(v1.w, c1, Sre[gi]);
                    Sim[gi] = fmaf(v1.w, s1, Sim[gi]);
                }
            }
            if (a < N) {
                float4 v0 = pb[a];
                #pragma unroll
                for (int gi = 0; gi < GPB; ++gi) {
                    float ph0 = fmaf(v0.x, kvx[gi], fmaf(v0.y, kvy[gi], v0.z * kvz[gi]));
                    float s0, c0;
                    __sincosf(ph0, &s0, &c0);
                    Sre[gi] = fmaf(v0.w, c0, Sre[gi]);
                    Sim[gi] = fmaf(v0.w, s0, Sim[gi]);
                }
            }

            #pragma unroll
            for (int gi = 0; gi < GPB; ++gi) {
                float sr = wave_reduce(Sre[gi]);
                float si = wave_reduce(Sim[gi]);
                if (lane == 0) { redA[w][gi] = sr; redB[w][gi] = si; }
            }
            __syncthreads();
            if (tid < 64) {
                float e = 0.f;
                if (tid < GPB) {
                    float SR = redA[0][tid] + redA[1][tid] + redA[2][tid] + redA[3][tid];
                    float SI = redB[0][tid] + redB[1][tid] + redB[2][tid] + redB[3][tid];
                    e = skv[tid].w * (SR * SR + SI * SI);
                }
                pval = wave_reduce(e);               // tid 0 holds the sum
            }
        }
        // dead block: pval stays 0
    } else {
        // ========================== real space =============================
        int rb = blk - CB;
        int t0 = rb * APB;
        sys  = t0 / N;                    // APB divides N
        slot = sys * stride + (rb - sys * RPS);
        const int Keff = KK ? KK : K;
        const float* C = cell + 9 * sys;

        float val = 0.0f;
        #pragma unroll 4
        for (int i = 0; i < APB/4; ++i) {
            int t = t0 + w * (APB/4) + i;
            float4 vi = pq[t];
            float xi = vi.x, yi = vi.y, zi = vi.z;
            float hqi = 0.5f * vi.w;
            if (lane == 0) val -= ALPHA * INV_SQRT_PI * vi.w * vi.w; // self term
            int nn = nnb[t];
            for (int k = lane; k < Keff; k += 64) {   // single trip when KK=64
                int p = t * Keff + k;
                int j = nm[p];
                bool msk = (j >= 0) && (k < nn);
                int js = j < 0 ? 0 : j;
                int sx = shifts[3*p], sy = shifts[3*p+1], sz = shifts[3*p+2];
                float4 vj = pq[js];
                float ox = 0.f, oy = 0.f, oz = 0.f;
                if ((sx | sy | sz) != 0) {           // uniform-false in practice
                    float fx = (float)sx, fy = (float)sy, fz = (float)sz;
                    ox = fx*C[0] + fy*C[3] + fz*C[6];
                    oy = fx*C[1] + fy*C[4] + fz*C[7];
                    oz = fx*C[2] + fy*C[5] + fz*C[8];
                }
                float dx = vj.x + ox - xi;
                float dy = vj.y + oy - yi;
                float dz = vj.z + oz - zi;
                float r2 = fmaf(dx, dx, fmaf(dy, dy, dz*dz));
                r2 = msk ? r2 : 1.0f;                // keep rsqrt finite
                float rinv = rsqrtf(r2);
                float d = r2 * rinv;
                float e = fast_erfc(ALPHA * d);
                float c = msk ? hqi * vj.w : 0.f;
                val = fmaf(c * rinv, e, val);
            }
        }

        val = wave_reduce(val);
        if (lane == 0) redr[w] = val;
        __syncthreads();
        if (tid == 0) pval = redr[0] + redr[1] + redr[2] + redr[3];
    }

    // ---------- merged epilogue: store partial, last block per system reduces
    if (tid == 0) {
        __hip_atomic_store(&partial[slot], pval, __ATOMIC_RELEASE,
                           __HIP_MEMORY_SCOPE_AGENT);
        int old = __hip_atomic_fetch_add(&done[sys], 1, __ATOMIC_ACQ_REL,
                                         __HIP_MEMORY_SCOPE_AGENT);
        sflag = (old == stride - 1);
    }
    __syncthreads();
    if (sflag) {
        float v = 0.f;
        for (int s = tid; s < stride; s += 256)
            v += __hip_atomic_load(&partial[sys * stride + s], __ATOMIC_RELAXED,
                                   __HIP_MEMORY_SCOPE_AGENT);
        v = wave_reduce(v);
        if (lane == 0) redf[w] = v;
        __syncthreads();
        if (tid == 0)
            out[sys] = 14.399645351950548f * (redf[0] + redf[1] + redf[2] + redf[3]);
    }
}

// =================== legacy fallback (tiny workspace) ======================
__global__ __launch_bounds__(256)
void ewald_legacy(const float* __restrict__ pos, const float* __restrict__ chg,
                  const float* __restrict__ cell, const int* __restrict__ nm,
                  const int* __restrict__ shifts, const int* __restrict__ nnb,
                  float* __restrict__ partial, int T, int N, int K, int Bn, int CB)
{
    __shared__ float red[16];
    const float TWO_PI  = 6.283185307179586f;
    const float ALPHA   = 0.3f;
    const float INV4A2  = 2.7777777777f;
    const float KC2     = 1.0f;
    const float INV_SQRT_PI = 0.5641895835477563f;
    int blk = blockIdx.x;

    if (blk < CB) {
        int gpb_groups = (GTOT + GPB - 1) / GPB;
        int b   = blk / gpb_groups;
        int grp = blk % gpb_groups;
        const float* C = cell + 9 * b;
        float m00=C[0], m01=C[1], m02=C[2];
        float m10=C[3], m11=C[4], m12=C[5];
        float m20=C[6], m21=C[7], m22=C[8];
        float a00 = m11*m22 - m12*m21;
        float a01 = m02*m21 - m01*m22;
        float a02 = m01*m12 - m02*m11;
        float a10 = m12*m20 - m10*m22;
        float a11 = m00*m22 - m02*m20;
        float a12 = m02*m10 - m00*m12;
        float a20 = m10*m21 - m11*m20;
        float a21 = m01*m20 - m00*m21;
        float a22 = m00*m11 - m01*m10;
        float det = m00*a00 + m01*a10 + m02*a20;
        float invdet = 1.0f / det;
        float vol = fabsf(det);

        float kvx[GPB], kvy[GPB], kvz[GPB], coef[GPB];
        bool any = false;
        #pragma unroll
        for (int gi = 0; gi < GPB; ++gi) {
            int g = grp * GPB + gi;
            float cf = 0.f, kx = 0.f, ky = 0.f, kz = 0.f;
            if (g < GTOT) {
                int ix = g / 81, rem = g - ix * 81;
                int iy = rem / 9, iz = rem - iy * 9;
                int nx = ix - 4, ny = iy - 4, nz = iz - 4;
                bool pos_half = (nx > 0) || (nx == 0 && (ny > 0 || (ny == 0 && nz > 0)));
                if (pos_half) {
                    float fx = (float)nx, fy = (float)ny, fz = (float)nz;
                    kx = TWO_PI * invdet * (fx*a00 + fy*a01 + fz*a02);
                    ky = TWO_PI * invdet * (fx*a10 + fy*a11 + fz*a12);
                    kz = TWO_PI * invdet * (fx*a20 + fy*a21 + fz*a22);
                    float k2 = kx*kx + ky*ky + kz*kz;
                    if (k2 > 1e-10f && k2 <= KC2)
                        cf = 12.566370614359172f * __expf(-k2 * INV4A2) / (k2 * vol);
                }
            }
            kvx[gi] = kx; kvy[gi] = ky; kvz[gi] = kz; coef[gi] = cf;
            any = any || (cf != 0.f);
        }
        int slot = b * STRIDE_LEG + (N / 16) + grp;
        if (!any) { if (threadIdx.x == 0) partial[slot] = 0.f; return; }

        float Sre[GPB], Sim[GPB];
        #pragma unroll
        for (int gi = 0; gi < GPB; ++gi) { Sre[gi] = 0.f; Sim[gi] = 0.f; }
        for (int a = threadIdx.x; a < N; a += 256) {
            const float* pp = pos + (size_t)3 * (b * N + a);
            float x = pp[0], y = pp[1], z = pp[2];
            float qa = chg[(size_t)b * N + a];
            #pragma unroll
            for (int gi = 0; gi < GPB; ++gi) {
                if (coef[gi] != 0.f) {
                    float ph = x*kvx[gi] + y*kvy[gi] + z*kvz[gi];
                    float s, c;
                    __sincosf(ph, &s, &c);
                    Sre[gi] = fmaf(qa, c, Sre[gi]);
                    Sim[gi] = fmaf(qa, s, Sim[gi]);
                }
            }
        }
        int lane = threadIdx.x & 63, w = threadIdx.x >> 6;
        float e_acc = 0.f;
        #pragma unroll
        for (int gi = 0; gi < GPB; ++gi) {
            if (coef[gi] != 0.f) {
                float sr = wave_reduce(Sre[gi]);
                float si = wave_reduce(Sim[gi]);
                if (lane == 0) { red[2*w] = sr; red[2*w+1] = si; }
                __syncthreads();
                if (threadIdx.x == 0) {
                    float SR = red[0] + red[2] + red[4] + red[6];
                    float SI = red[1] + red[3] + red[5] + red[7];
                    e_acc += coef[gi] * (SR*SR + SI*SI);
                }
                __syncthreads();
            }
        }
        if (threadIdx.x == 0) partial[slot] = e_acc;
    } else {
        int rb = blk - CB;
        int t0 = rb * 16;
        int sys = t0 / N;
        int lane = threadIdx.x & 63, w = threadIdx.x >> 6;
        float val = 0.0f;
        #pragma unroll
        for (int i = 0; i < 4; ++i) {
            int t = t0 + w * 4 + i;
            float xi = pos[3*t], yi = pos[3*t+1], zi = pos[3*t+2];
            float qi = chg[t];
            if (lane == 0) val -= ALPHA * INV_SQRT_PI * qi * qi;
            int nn = nnb[t];
            for (int k = lane; k < K; k += 64) {
                int p = t * K + k;
                int j = nm[p];
                bool msk = (j >= 0) && (k < nn);
                if (msk) {
                    int sx = shifts[3*p], sy = shifts[3*p+1], sz = shifts[3*p+2];
                    float ox = 0.f, oy = 0.f, oz = 0.f;
                    if ((sx | sy | sz) != 0) {
                        const float* C = cell + 9 * sys;
                        float fx = (float)sx, fy = (float)sy, fz = (float)sz;
                        ox = fx*C[0] + fy*C[3] + fz*C[6];
                        oy = fx*C[1] + fy*C[4] + fz*C[7];
                        oz = fx*C[2] + fy*C[5] + fz*C[8];
                    }
                    float dx = pos[3*j] + ox - xi;
                    float dy = pos[3*j+1] + oy - yi;
                    float dz = pos[3*j+2] + oz - zi;
                    float r2 = fmaf(dx, dx, fmaf(dy, dy, dz*dz));
                    float rinv = rsqrtf(r2);
                    float d = r2 * rinv;
                    val += 0.5f * qi * chg[j] * fast_erfc(ALPHA * d) * rinv;
                }
            }
        }
        val = wave_reduce(val);
        if (lane == 0) red[w] = val;
        __syncthreads();
        if (threadIdx.x == 0) {
            int rb_in_sys = rb - sys * (N / 16);
            partial[sys * STRIDE_LEG + rb_in_sys] = red[0] + red[1] + red[2] + red[3];
        }
    }
}

__global__ __launch_bounds__(256)
void final_reduce(const float* __restrict__ partial, float* __restrict__ out,
                  int nslots, int stride)
{
    __shared__ float red[4];
    const float COUL = 14.399645351950548f;
    int b = blockIdx.x;
    float v = 0.f;
    for (int s = threadIdx.x; s < nslots; s += 256)
        v += partial[b * stride + s];
    v = wave_reduce(v);
    int lane = threadIdx.x & 63, w = threadIdx.x >> 6;
    if (lane == 0) red[w] = v;
    __syncthreads();
    if (threadIdx.x == 0)
        out[b] = COUL * (red[0] + red[1] + red[2] + red[3]);
}

extern "C" void kernel_launch(void* const* d_in, const int* in_sizes, int n_in,
                              void* d_out, int out_size, void* d_ws, size_t ws_size,
                              hipStream_t stream) {
    const float* pos    = (const float*)d_in[0];
    const float* chg    = (const float*)d_in[1];
    const float* cellp  = (const float*)d_in[2];
    const int*   nm     = (const int*)d_in[3];
    const int*   shifts = (const int*)d_in[4];
    const int*   nnb    = (const int*)d_in[5];

    int T  = in_sizes[1];          // 64000
    int Bn = in_sizes[2] / 9;      // 16
    int N  = T / Bn;               // 4000
    int K  = in_sizes[3] / T;      // 64

    // workspace layout: partial | pq (float4) | kcomp (float4) | kcnt | done
    int RPS = N / APB;                         // real partial slots / system (50)
    int stride = RPS + GMAX;                   // 96
    size_t partBytes = (size_t)Bn * stride * sizeof(float);
    size_t pqOff     = ((partBytes + 255) / 256) * 256;
    size_t pqBytes   = (size_t)T * sizeof(float4);
    size_t kOff      = ((pqOff + pqBytes + 255) / 256) * 256;
    size_t kBytes    = (size_t)Bn * KMAX * sizeof(float4);
    size_t cntOff    = kOff + kBytes;
    size_t doneOff   = cntOff + ((size_t)Bn * sizeof(int) + 63) / 64 * 64;
    size_t needed    = doneOff + (size_t)Bn * sizeof(int);

    if ((N % APB) == 0 && ws_size >= needed) {
        float*  partial = (float*)d_ws;
        float4* pq      = (float4*)((char*)d_ws + pqOff);
        float4* kcomp   = (float4*)((char*)d_ws + kOff);
        int*    kcnt    = (int*)((char*)d_ws + cntOff);
        int*    done    = (int*)((char*)d_ws + doneOff);

        int PB = (T + 255) / 256;              // 250 pack blocks
        int CB = Bn * GMAX;                    // 736 recip blocks
        int RB = T / APB;                      // 800 real blocks

        prologue<<<PB + Bn, 256, 0, stream>>>(pos, chg, pq, cellp, kcomp, kcnt,
                                              done, T, PB);
        if (K == 64)
            ewald_main<64><<<CB + RB, 256, 0, stream>>>(
                pq, cellp, nm, shifts, nnb, kcomp, kcnt, partial, done,
                (float*)d_out, T, N, K, Bn, CB, RPS);
        else
            ewald_main<0><<<CB + RB, 256, 0, stream>>>(
                pq, cellp, nm, shifts, nnb, kcomp, kcnt, partial, done,
                (float*)d_out, T, N, K, Bn, CB, RPS);
    } else {
        // legacy path: no packing, no compaction, 2 kernels, tiny workspace
        float* partial = (float*)d_ws;
        int CB = Bn * ((GTOT + GPB - 1) / GPB);
        int RB = T / 16;
        int nslots = (N / 16) + ((GTOT + GPB - 1) / GPB);
        ewald_legacy<<<CB + RB, 256, 0, stream>>>(pos, chg, cellp, nm, shifts,
                                                  nnb, partial, T, N, K, Bn, CB);
        final_reduce<<<Bn, 256, 0, stream>>>(partial, (float*)d_out, nslots,
                                             STRIDE_LEG);
    }
}

// Round 5
// 123.899 us; speedup vs baseline: 1.6045x; 1.6045x over previous
//
#include <hip/hip_runtime.h>
#include <math.h>

// Problem constants (match reference config)
#define GPB    8                 // k-vectors per reciprocal block
#define GTOT   729               // (2*NMAX+1)^3, NMAX=4
#define GMAX   46                // ceil(364/8): worst-case active half-sphere k's / GPB
#define KMAX   (GMAX*GPB)        // compacted k slots per system (padded)
#define APB    16                // atoms per real block (256 thr = 4 waves x 4 atoms)
#define STRIDE 344               // partial slots per system: 250 real + 46 recip (padded)

__device__ __forceinline__ float wave_reduce(float v) {
    #pragma unroll
    for (int off = 32; off > 0; off >>= 1) v += __shfl_down(v, off, 64);
    return v;
}

// Abramowitz & Stegun 7.1.26: erfc(x) for x>=0, |abs err| <= 1.5e-7.
__device__ __forceinline__ float fast_erfc(float x) {
    float t = __builtin_amdgcn_rcpf(fmaf(0.3275911f, x, 1.0f));
    float p = fmaf(1.061405429f, t, -1.453152027f);
    p = fmaf(p, t, 1.421413741f);
    p = fmaf(p, t, -0.284496736f);
    p = fmaf(p, t, 0.254829592f);
    return p * t * __expf(-x * x);
}

// ---------- prologue: pack pq (PB blocks) + compact k-vectors (Bn blocks) ---
// NOTE: recip energy is quadratic in S(k) -> the FULL atom sum must stay in
// one block per (system, k-group). Do NOT slice the atom loop (round-4 bug).
__global__ __launch_bounds__(256)
void prologue(const float* __restrict__ pos, const float* __restrict__ chg,
              float4* __restrict__ pq, const float* __restrict__ cell,
              float4* __restrict__ kcomp, int* __restrict__ kcnt,
              int T, int PB)
{
    int blk = blockIdx.x;
    if (blk < PB) {
        int t = blk * 256 + threadIdx.x;
        if (t < T)
            pq[t] = make_float4(pos[3*t], pos[3*t+1], pos[3*t+2], chg[t]);
        return;
    }
    // one system per block; wave 0 does the compaction scan
    int b = blk - PB;
    if (threadIdx.x >= 64) return;

    const float TWO_PI = 6.283185307179586f;
    const float INV4A2 = 2.7777777777f;          // 1/(4*ALPHA^2)
    const float KC2    = 1.0f;
    int lane = threadIdx.x;

    const float* C = cell + 9 * b;
    float m00=C[0], m01=C[1], m02=C[2];
    float m10=C[3], m11=C[4], m12=C[5];
    float m20=C[6], m21=C[7], m22=C[8];
    float a00 = m11*m22 - m12*m21;
    float a01 = m02*m21 - m01*m22;
    float a02 = m01*m12 - m02*m11;
    float a10 = m12*m20 - m10*m22;
    float a11 = m00*m22 - m02*m20;
    float a12 = m02*m10 - m00*m12;
    float a20 = m10*m21 - m11*m20;
    float a21 = m01*m20 - m00*m21;
    float a22 = m00*m11 - m01*m10;
    float det = m00*a00 + m01*a10 + m02*a20;
    float invdet = 1.0f / det;
    float vol = fabsf(det);

    int cnt = 0;
    for (int base = 0; base < GTOT; base += 64) {
        int g = base + lane;
        float kx = 0.f, ky = 0.f, kz = 0.f, cf = 0.f;
        if (g < GTOT) {
            int ix = g / 81, rem = g - ix * 81;
            int iy = rem / 9, iz = rem - iy * 9;
            int nx = ix - 4, ny = iy - 4, nz = iz - 4;
            // half-sphere: keep lexicographically-positive n, double coef
            bool pos_half = (nx > 0) || (nx == 0 && (ny > 0 || (ny == 0 && nz > 0)));
            if (pos_half) {
                float fx = (float)nx, fy = (float)ny, fz = (float)nz;
                kx = TWO_PI * invdet * (fx*a00 + fy*a01 + fz*a02);
                ky = TWO_PI * invdet * (fx*a10 + fy*a11 + fz*a12);
                kz = TWO_PI * invdet * (fx*a20 + fy*a21 + fz*a22);
                float k2 = kx*kx + ky*ky + kz*kz;
                if (k2 > 1e-10f && k2 <= KC2) {
                    // 2 * [4*pi*exp(-k2/4a^2)/k2] / (2*vol)  (half-sphere doubling)
                    cf = 12.566370614359172f * __expf(-k2 * INV4A2) / (k2 * vol);
                }
            }
        }
        bool act = (cf != 0.f);
        unsigned long long m = __ballot(act);
        if (act) {
            int off = __popcll(m & ((1ull << lane) - 1ull));
            kcomp[b * KMAX + cnt + off] = make_float4(kx, ky, kz, cf);
        }
        cnt += (int)__popcll(m);
    }
    // pad to a multiple of GPB with dead entries so groups unroll densely
    int padded = ((cnt + GPB - 1) / GPB) * GPB;
    if (lane < padded - cnt)
        kcomp[b * KMAX + cnt + lane] = make_float4(0.f, 0.f, 0.f, 0.f);
    if (lane == 0) kcnt[b] = padded / GPB;
}

// ---------- fused main kernel (verified round-1 structure, unsliced) --------
__global__ __launch_bounds__(256)
void ewald_fused2(const float4* __restrict__ pq,    // packed [T]
                  const float*  __restrict__ cell,  // [Bn,3,3]
                  const int*    __restrict__ nm,    // [T,K]
                  const int*    __restrict__ shifts,// [T,K,3]
                  const int*    __restrict__ nnb,   // [T]
                  const float4* __restrict__ kcomp, // [Bn,KMAX]
                  const int*    __restrict__ kcnt,  // [Bn]
                  float* __restrict__ partial,      // [Bn][STRIDE]
                  int T, int N, int K, int Bn, int CB)
{
    __shared__ float4 skv[GPB];
    __shared__ float  redA[4][GPB];
    __shared__ float  redB[4][GPB];
    __shared__ float  redr[4];

    const float ALPHA       = 0.3f;
    const float INV_SQRT_PI = 0.5641895835477563f;

    int blk  = blockIdx.x;
    int tid  = threadIdx.x;
    int lane = tid & 63;
    int w    = tid >> 6;

    if (blk < CB) {
        // ======================= reciprocal space ==========================
        int b    = blk / GMAX;
        int grp  = blk - b * GMAX;
        int slot = b * STRIDE + (N / APB) + grp;
        int ng   = kcnt[b];
        if (grp >= ng) {                           // dead block: no atom loop
            if (tid == 0) partial[slot] = 0.f;
            return;
        }

        if (tid < GPB)
            skv[tid] = kcomp[b * KMAX + grp * GPB + tid];
        __syncthreads();

        float kvx[GPB], kvy[GPB], kvz[GPB];
        #pragma unroll
        for (int gi = 0; gi < GPB; ++gi) {
            float4 v = skv[gi];
            kvx[gi] = v.x; kvy[gi] = v.y; kvz[gi] = v.z;
        }

        float Sre[GPB], Sim[GPB];
        #pragma unroll
        for (int gi = 0; gi < GPB; ++gi) { Sre[gi] = 0.f; Sim[gi] = 0.f; }

        // dense inner loop over ALL N atoms, 2 atoms per iteration
        const float4* pb = pq + (size_t)b * N;
        int a = tid;
        for (; a + 256 < N; a += 512) {
            float4 v0 = pb[a];
            float4 v1 = pb[a + 256];
            #pragma unroll
            for (int gi = 0; gi < GPB; ++gi) {
                float ph0 = fmaf(v0.x, kvx[gi], fmaf(v0.y, kvy[gi], v0.z * kvz[gi]));
                float ph1 = fmaf(v1.x, kvx[gi], fmaf(v1.y, kvy[gi], v1.z * kvz[gi]));
                float s0, c0, s1, c1;
                __sincosf(ph0, &s0, &c0);
                __sincosf(ph1, &s1, &c1);
                Sre[gi] = fmaf(v0.w, c0, Sre[gi]);
                Sim[gi] = fmaf(v0.w, s0, Sim[gi]);
                Sre[gi] = fmaf(v1.w, c1, Sre[gi]);
                Sim[gi] = fmaf(v1.w, s1, Sim[gi]);
            }
        }
        if (a < N) {                               // tail atom
            float4 v0 = pb[a];
            #pragma unroll
            for (int gi = 0; gi < GPB; ++gi) {
                float ph0 = fmaf(v0.x, kvx[gi], fmaf(v0.y, kvy[gi], v0.z * kvz[gi]));
                float s0, c0;
                __sincosf(ph0, &s0, &c0);
                Sre[gi] = fmaf(v0.w, c0, Sre[gi]);
                Sim[gi] = fmaf(v0.w, s0, Sim[gi]);
            }
        }

        // single-sync reduction: wave partials -> LDS -> wave 0 finishes
        #pragma unroll
        for (int gi = 0; gi < GPB; ++gi) {
            float sr = wave_reduce(Sre[gi]);
            float si = wave_reduce(Sim[gi]);
            if (lane == 0) { redA[w][gi] = sr; redB[w][gi] = si; }
        }
        __syncthreads();
        if (tid < 64) {
            float e = 0.f;
            if (tid < GPB) {
                float SR = redA[0][tid] + redA[1][tid] + redA[2][tid] + redA[3][tid];
                float SI = redB[0][tid] + redB[1][tid] + redB[2][tid] + redB[3][tid];
                e = skv[tid].w * (SR * SR + SI * SI);
            }
            e = wave_reduce(e);
            if (tid == 0) partial[slot] = e;
        }
    } else {
        // ========================== real space =============================
        int rb = blk - CB;
        int t0 = rb * APB;
        int sys = t0 / N;                 // APB divides N -> block in one system

        float val = 0.0f;
        #pragma unroll
        for (int i = 0; i < APB/4; ++i) {
            int t = t0 + w * (APB/4) + i;
            float4 vi = pq[t];
            float xi = vi.x, yi = vi.y, zi = vi.z, qi = vi.w;
            if (lane == 0) val -= ALPHA * INV_SQRT_PI * qi * qi; // self term
            int nn = nnb[t];
            for (int k = lane; k < K; k += 64) {
                int p = t * K + k;
                int j = nm[p];
                bool msk = (j >= 0) && (k < nn);
                if (msk) {
                    int sx = shifts[3*p], sy = shifts[3*p+1], sz = shifts[3*p+2];
                    float ox = 0.f, oy = 0.f, oz = 0.f;
                    if ((sx | sy | sz) != 0) {
                        const float* C = cell + 9 * sys;
                        float fx = (float)sx, fy = (float)sy, fz = (float)sz;
                        ox = fx*C[0] + fy*C[3] + fz*C[6];
                        oy = fx*C[1] + fy*C[4] + fz*C[7];
                        oz = fx*C[2] + fy*C[5] + fz*C[8];
                    }
                    float4 vj = pq[j];
                    float dx = vj.x + ox - xi;
                    float dy = vj.y + oy - yi;
                    float dz = vj.z + oz - zi;
                    float r2 = fmaf(dx, dx, fmaf(dy, dy, dz*dz));
                    float rinv = rsqrtf(r2);
                    float d = r2 * rinv;
                    val += 0.5f * qi * vj.w * fast_erfc(ALPHA * d) * rinv;
                }
            }
        }

        val = wave_reduce(val);
        if (lane == 0) redr[w] = val;
        __syncthreads();
        if (tid == 0) {
            int rb_in_sys = rb - sys * (N / APB);
            partial[sys * STRIDE + rb_in_sys] =
                redr[0] + redr[1] + redr[2] + redr[3];
        }
    }
}

// -------- epilogue: per-system sum of partials, apply Coulomb constant -----
__global__ __launch_bounds__(256)
void final_reduce(const float* __restrict__ partial, float* __restrict__ out,
                  int nslots)
{
    __shared__ float red[4];
    const float COUL = 14.399645351950548f;
    int b = blockIdx.x;
    float v = 0.f;
    for (int s = threadIdx.x; s < nslots; s += 256)
        v += partial[b * STRIDE + s];
    v = wave_reduce(v);
    int lane = threadIdx.x & 63, w = threadIdx.x >> 6;
    if (lane == 0) red[w] = v;
    __syncthreads();
    if (threadIdx.x == 0)
        out[b] = COUL * (red[0] + red[1] + red[2] + red[3]);
}

// =================== legacy fallback (tiny workspace) ======================
__global__ __launch_bounds__(256)
void ewald_legacy(const float* __restrict__ pos, const float* __restrict__ chg,
                  const float* __restrict__ cell, const int* __restrict__ nm,
                  const int* __restrict__ shifts, const int* __restrict__ nnb,
                  float* __restrict__ partial, int T, int N, int K, int Bn, int CB)
{
    __shared__ float red[16];
    const float TWO_PI  = 6.283185307179586f;
    const float ALPHA   = 0.3f;
    const float INV4A2  = 2.7777777777f;
    const float KC2     = 1.0f;
    const float INV_SQRT_PI = 0.5641895835477563f;
    int blk = blockIdx.x;

    if (blk < CB) {
        int gpb_groups = (GTOT + GPB - 1) / GPB;
        int b   = blk / gpb_groups;
        int grp = blk % gpb_groups;
        const float* C = cell + 9 * b;
        float m00=C[0], m01=C[1], m02=C[2];
        float m10=C[3], m11=C[4], m12=C[5];
        float m20=C[6], m21=C[7], m22=C[8];
        float a00 = m11*m22 - m12*m21;
        float a01 = m02*m21 - m01*m22;
        float a02 = m01*m12 - m02*m11;
        float a10 = m12*m20 - m10*m22;
        float a11 = m00*m22 - m02*m20;
        float a12 = m02*m10 - m00*m12;
        float a20 = m10*m21 - m11*m20;
        float a21 = m01*m20 - m00*m21;
        float a22 = m00*m11 - m01*m10;
        float det = m00*a00 + m01*a10 + m02*a20;
        float invdet = 1.0f / det;
        float vol = fabsf(det);

        float kvx[GPB], kvy[GPB], kvz[GPB], coef[GPB];
        bool any = false;
        #pragma unroll
        for (int gi = 0; gi < GPB; ++gi) {
            int g = grp * GPB + gi;
            float cf = 0.f, kx = 0.f, ky = 0.f, kz = 0.f;
            if (g < GTOT) {
                int ix = g / 81, rem = g - ix * 81;
                int iy = rem / 9, iz = rem - iy * 9;
                int nx = ix - 4, ny = iy - 4, nz = iz - 4;
                bool pos_half = (nx > 0) || (nx == 0 && (ny > 0 || (ny == 0 && nz > 0)));
                if (pos_half) {
                    float fx = (float)nx, fy = (float)ny, fz = (float)nz;
                    kx = TWO_PI * invdet * (fx*a00 + fy*a01 + fz*a02);
                    ky = TWO_PI * invdet * (fx*a10 + fy*a11 + fz*a12);
                    kz = TWO_PI * invdet * (fx*a20 + fy*a21 + fz*a22);
                    float k2 = kx*kx + ky*ky + kz*kz;
                    if (k2 > 1e-10f && k2 <= KC2)
                        cf = 12.566370614359172f * __expf(-k2 * INV4A2) / (k2 * vol);
                }
            }
            kvx[gi] = kx; kvy[gi] = ky; kvz[gi] = kz; coef[gi] = cf;
            any = any || (cf != 0.f);
        }
        int slot = b * STRIDE + (N / APB) + grp;
        if (!any) { if (threadIdx.x == 0) partial[slot] = 0.f; return; }

        float Sre[GPB], Sim[GPB];
        #pragma unroll
        for (int gi = 0; gi < GPB; ++gi) { Sre[gi] = 0.f; Sim[gi] = 0.f; }
        for (int a = threadIdx.x; a < N; a += 256) {
            const float* pp = pos + (size_t)3 * (b * N + a);
            float x = pp[0], y = pp[1], z = pp[2];
            float qa = chg[(size_t)b * N + a];
            #pragma unroll
            for (int gi = 0; gi < GPB; ++gi) {
                if (coef[gi] != 0.f) {
                    float ph = x*kvx[gi] + y*kvy[gi] + z*kvz[gi];
                    float s, c;
                    __sincosf(ph, &s, &c);
                    Sre[gi] = fmaf(qa, c, Sre[gi]);
                    Sim[gi] = fmaf(qa, s, Sim[gi]);
                }
            }
        }
        int lane = threadIdx.x & 63, w = threadIdx.x >> 6;
        float e_acc = 0.f;
        #pragma unroll
        for (int gi = 0; gi < GPB; ++gi) {
            if (coef[gi] != 0.f) {
                float sr = wave_reduce(Sre[gi]);
                float si = wave_reduce(Sim[gi]);
                if (lane == 0) { red[2*w] = sr; red[2*w+1] = si; }
                __syncthreads();
                if (threadIdx.x == 0) {
                    float SR = red[0] + red[2] + red[4] + red[6];
                    float SI = red[1] + red[3] + red[5] + red[7];
                    e_acc += coef[gi] * (SR*SR + SI*SI);
                }
                __syncthreads();
            }
        }
        if (threadIdx.x == 0) partial[slot] = e_acc;
    } else {
        int rb = blk - CB;
        int t0 = rb * APB;
        int sys = t0 / N;
        int lane = threadIdx.x & 63, w = threadIdx.x >> 6;
        float val = 0.0f;
        #pragma unroll
        for (int i = 0; i < APB/4; ++i) {
            int t = t0 + w * (APB/4) + i;
            float xi = pos[3*t], yi = pos[3*t+1], zi = pos[3*t+2];
            float qi = chg[t];
            if (lane == 0) val -= ALPHA * INV_SQRT_PI * qi * qi;
            int nn = nnb[t];
            for (int k = lane; k < K; k += 64) {
                int p = t * K + k;
                int j = nm[p];
                bool msk = (j >= 0) && (k < nn);
                if (msk) {
                    int sx = shifts[3*p], sy = shifts[3*p+1], sz = shifts[3*p+2];
                    float ox = 0.f, oy = 0.f, oz = 0.f;
                    if ((sx | sy | sz) != 0) {
                        const float* C = cell + 9 * sys;
                        float fx = (float)sx, fy = (float)sy, fz = (float)sz;
                        ox = fx*C[0] + fy*C[3] + fz*C[6];
                        oy = fx*C[1] + fy*C[4] + fz*C[7];
                        oz = fx*C[2] + fy*C[5] + fz*C[8];
                    }
                    float dx = pos[3*j] + ox - xi;
                    float dy = pos[3*j+1] + oy - yi;
                    float dz = pos[3*j+2] + oz - zi;
                    float r2 = fmaf(dx, dx, fmaf(dy, dy, dz*dz));
                    float rinv = rsqrtf(r2);
                    float d = r2 * rinv;
                    val += 0.5f * qi * chg[j] * fast_erfc(ALPHA * d) * rinv;
                }
            }
        }
        val = wave_reduce(val);
        if (lane == 0) red[w] = val;
        __syncthreads();
        if (threadIdx.x == 0) {
            int rb_in_sys = rb - sys * (N / APB);
            partial[sys * STRIDE + rb_in_sys] = red[0] + red[1] + red[2] + red[3];
        }
    }
}

extern "C" void kernel_launch(void* const* d_in, const int* in_sizes, int n_in,
                              void* d_out, int out_size, void* d_ws, size_t ws_size,
                              hipStream_t stream) {
    const float* pos    = (const float*)d_in[0];
    const float* chg    = (const float*)d_in[1];
    const float* cellp  = (const float*)d_in[2];
    const int*   nm     = (const int*)d_in[3];
    const int*   shifts = (const int*)d_in[4];
    const int*   nnb    = (const int*)d_in[5];

    int T  = in_sizes[1];          // 64000
    int Bn = in_sizes[2] / 9;      // 16
    int N  = T / Bn;               // 4000
    int K  = in_sizes[3] / T;      // 64

    // workspace layout: partial | pq (float4) | kcomp (float4) | kcnt
    size_t partBytes = (size_t)Bn * STRIDE * sizeof(float);
    size_t pqOff     = ((partBytes + 255) / 256) * 256;
    size_t pqBytes   = (size_t)T * sizeof(float4);
    size_t kOff      = ((pqOff + pqBytes + 255) / 256) * 256;
    size_t kBytes    = (size_t)Bn * KMAX * sizeof(float4);
    size_t cntOff    = kOff + kBytes;
    size_t needed    = cntOff + (size_t)Bn * sizeof(int);

    if ((N % APB) == 0 && ws_size >= needed) {
        float*  partial = (float*)d_ws;
        float4* pq      = (float4*)((char*)d_ws + pqOff);
        float4* kcomp   = (float4*)((char*)d_ws + kOff);
        int*    kcnt    = (int*)((char*)d_ws + cntOff);

        int PB = (T + 255) / 256;              // 250 pack blocks
        int CB = Bn * GMAX;                    // 736 recip blocks (some early-exit)
        int RB = T / APB;                      // 4000 real blocks
        int nslots = (N / APB) + GMAX;         // 296

        prologue<<<PB + Bn, 256, 0, stream>>>(pos, chg, pq, cellp, kcomp, kcnt,
                                              T, PB);
        ewald_fused2<<<CB + RB, 256, 0, stream>>>(
            pq, cellp, nm, shifts, nnb, kcomp, kcnt, partial, T, N, K, Bn, CB);
        final_reduce<<<Bn, 256, 0, stream>>>(partial, (float*)d_out, nslots);
    } else {
        // legacy path: no packing, no compaction, 2 kernels, tiny workspace
        float* partial = (float*)d_ws;
        int CB = Bn * ((GTOT + GPB - 1) / GPB);
        int RB = T / APB;
        int nslots = (N / APB) + ((GTOT + GPB - 1) / GPB);
        ewald_legacy<<<CB + RB, 256, 0, stream>>>(pos, chg, cellp, nm, shifts,
                                                  nnb, partial, T, N, K, Bn, CB);
        final_reduce<<<Bn, 256, 0, stream>>>(partial, (float*)d_out, nslots);
    }
}

// Round 6
// 120.039 us; speedup vs baseline: 1.6561x; 1.0322x over previous
//
#include <hip/hip_runtime.h>
#include <math.h>

// Problem constants (match reference config)
#define GPB    8                 // k-vectors per reciprocal block
#define GTOT   729               // (2*NMAX+1)^3, NMAX=4
#define GMAX   46                // ceil(364/8): worst-case active half-sphere k's / GPB
#define KMAX   (GMAX*GPB)        // compacted k slots per system (padded)
#define APB    16                // atoms per real block (256 thr = 4 waves x 4 atoms)
#define STRIDE 344               // partial slots per system: 250 real + 46 recip (padded)

__device__ __forceinline__ float wave_reduce(float v) {
    #pragma unroll
    for (int off = 32; off > 0; off >>= 1) v += __shfl_down(v, off, 64);
    return v;
}

// Abramowitz & Stegun 7.1.26: erfc(x) for x>=0, |abs err| <= 1.5e-7.
__device__ __forceinline__ float fast_erfc(float x) {
    float t = __builtin_amdgcn_rcpf(fmaf(0.3275911f, x, 1.0f));
    float p = fmaf(1.061405429f, t, -1.453152027f);
    p = fmaf(p, t, 1.421413741f);
    p = fmaf(p, t, -0.284496736f);
    p = fmaf(p, t, 0.254829592f);
    return p * t * __expf(-x * x);
}

// ---------- prologue: pack pq (PB blocks) + compact k-vectors (Bn blocks) ---
// NOTE: recip energy is quadratic in S(k) -> the FULL atom sum must stay in
// one block per (system, k-group). Do NOT slice the atom loop (round-4 bug).
__global__ __launch_bounds__(256)
void prologue(const float* __restrict__ pos, const float* __restrict__ chg,
              float4* __restrict__ pq, const float* __restrict__ cell,
              float4* __restrict__ kcomp, int* __restrict__ kcnt,
              int T, int PB)
{
    int blk = blockIdx.x;
    if (blk < PB) {
        int t = blk * 256 + threadIdx.x;
        if (t < T)
            pq[t] = make_float4(pos[3*t], pos[3*t+1], pos[3*t+2], chg[t]);
        return;
    }
    // one system per block; wave 0 does the compaction scan
    int b = blk - PB;
    if (threadIdx.x >= 64) return;

    const float TWO_PI = 6.283185307179586f;
    const float INV4A2 = 2.7777777777f;          // 1/(4*ALPHA^2)
    const float KC2    = 1.0f;
    int lane = threadIdx.x;

    const float* C = cell + 9 * b;
    float m00=C[0], m01=C[1], m02=C[2];
    float m10=C[3], m11=C[4], m12=C[5];
    float m20=C[6], m21=C[7], m22=C[8];
    float a00 = m11*m22 - m12*m21;
    float a01 = m02*m21 - m01*m22;
    float a02 = m01*m12 - m02*m11;
    float a10 = m12*m20 - m10*m22;
    float a11 = m00*m22 - m02*m20;
    float a12 = m02*m10 - m00*m12;
    float a20 = m10*m21 - m11*m20;
    float a21 = m01*m20 - m00*m21;
    float a22 = m00*m11 - m01*m10;
    float det = m00*a00 + m01*a10 + m02*a20;
    float invdet = 1.0f / det;
    float vol = fabsf(det);

    int cnt = 0;
    for (int base = 0; base < GTOT; base += 64) {
        int g = base + lane;
        float kx = 0.f, ky = 0.f, kz = 0.f, cf = 0.f;
        if (g < GTOT) {
            int ix = g / 81, rem = g - ix * 81;
            int iy = rem / 9, iz = rem - iy * 9;
            int nx = ix - 4, ny = iy - 4, nz = iz - 4;
            // half-sphere: keep lexicographically-positive n, double coef
            bool pos_half = (nx > 0) || (nx == 0 && (ny > 0 || (ny == 0 && nz > 0)));
            if (pos_half) {
                float fx = (float)nx, fy = (float)ny, fz = (float)nz;
                kx = TWO_PI * invdet * (fx*a00 + fy*a01 + fz*a02);
                ky = TWO_PI * invdet * (fx*a10 + fy*a11 + fz*a12);
                kz = TWO_PI * invdet * (fx*a20 + fy*a21 + fz*a22);
                float k2 = kx*kx + ky*ky + kz*kz;
                if (k2 > 1e-10f && k2 <= KC2) {
                    // 2 * [4*pi*exp(-k2/4a^2)/k2] / (2*vol)  (half-sphere doubling)
                    cf = 12.566370614359172f * __expf(-k2 * INV4A2) / (k2 * vol);
                }
            }
        }
        bool act = (cf != 0.f);
        unsigned long long m = __ballot(act);
        if (act) {
            int off = __popcll(m & ((1ull << lane) - 1ull));
            kcomp[b * KMAX + cnt + off] = make_float4(kx, ky, kz, cf);
        }
        cnt += (int)__popcll(m);
    }
    // pad to a multiple of GPB with dead entries so groups unroll densely
    int padded = ((cnt + GPB - 1) / GPB) * GPB;
    if (lane < padded - cnt)
        kcomp[b * KMAX + cnt + lane] = make_float4(0.f, 0.f, 0.f, 0.f);
    if (lane == 0) kcnt[b] = padded / GPB;
}

// ---------- fused main kernel; KK = compile-time K (0 -> runtime loop) ------
template <int KK>
__global__ __launch_bounds__(256)
void ewald_fused2(const float4* __restrict__ pq,    // packed [T]
                  const float*  __restrict__ cell,  // [Bn,3,3]
                  const int*    __restrict__ nm,    // [T,K]
                  const int*    __restrict__ shifts,// [T,K,3]
                  const int*    __restrict__ nnb,   // [T]
                  const float4* __restrict__ kcomp, // [Bn,KMAX]
                  const int*    __restrict__ kcnt,  // [Bn]
                  float* __restrict__ partial,      // [Bn][STRIDE]
                  int T, int N, int K, int Bn, int CB)
{
    __shared__ float4 skv[GPB];
    __shared__ float  redA[4][GPB];
    __shared__ float  redB[4][GPB];
    __shared__ float  redr[4];

    const float ALPHA       = 0.3f;
    const float INV_SQRT_PI = 0.5641895835477563f;

    int blk  = blockIdx.x;
    int tid  = threadIdx.x;
    int lane = tid & 63;
    int w    = tid >> 6;

    if (blk < CB) {
        // ======================= reciprocal space ==========================
        int b    = blk / GMAX;
        int grp  = blk - b * GMAX;
        int slot = b * STRIDE + (N / APB) + grp;
        int ng   = kcnt[b];
        if (grp >= ng) {                           // dead block: no atom loop
            if (tid == 0) partial[slot] = 0.f;
            return;
        }

        if (tid < GPB)
            skv[tid] = kcomp[b * KMAX + grp * GPB + tid];
        __syncthreads();

        float kvx[GPB], kvy[GPB], kvz[GPB];
        #pragma unroll
        for (int gi = 0; gi < GPB; ++gi) {
            float4 v = skv[gi];
            kvx[gi] = v.x; kvy[gi] = v.y; kvz[gi] = v.z;
        }

        float Sre[GPB], Sim[GPB];
        #pragma unroll
        for (int gi = 0; gi < GPB; ++gi) { Sre[gi] = 0.f; Sim[gi] = 0.f; }

        // dense inner loop over ALL N atoms, 2 atoms per iteration
        const float4* pb = pq + (size_t)b * N;
        int a = tid;
        for (; a + 256 < N; a += 512) {
            float4 v0 = pb[a];
            float4 v1 = pb[a + 256];
            #pragma unroll
            for (int gi = 0; gi < GPB; ++gi) {
                float ph0 = fmaf(v0.x, kvx[gi], fmaf(v0.y, kvy[gi], v0.z * kvz[gi]));
                float ph1 = fmaf(v1.x, kvx[gi], fmaf(v1.y, kvy[gi], v1.z * kvz[gi]));
                float s0, c0, s1, c1;
                __sincosf(ph0, &s0, &c0);
                __sincosf(ph1, &s1, &c1);
                Sre[gi] = fmaf(v0.w, c0, Sre[gi]);
                Sim[gi] = fmaf(v0.w, s0, Sim[gi]);
                Sre[gi] = fmaf(v1.w, c1, Sre[gi]);
                Sim[gi] = fmaf(v1.w, s1, Sim[gi]);
            }
        }
        if (a < N) {                               // tail atom
            float4 v0 = pb[a];
            #pragma unroll
            for (int gi = 0; gi < GPB; ++gi) {
                float ph0 = fmaf(v0.x, kvx[gi], fmaf(v0.y, kvy[gi], v0.z * kvz[gi]));
                float s0, c0;
                __sincosf(ph0, &s0, &c0);
                Sre[gi] = fmaf(v0.w, c0, Sre[gi]);
                Sim[gi] = fmaf(v0.w, s0, Sim[gi]);
            }
        }

        // single-sync reduction: wave partials -> LDS -> wave 0 finishes
        #pragma unroll
        for (int gi = 0; gi < GPB; ++gi) {
            float sr = wave_reduce(Sre[gi]);
            float si = wave_reduce(Sim[gi]);
            if (lane == 0) { redA[w][gi] = sr; redB[w][gi] = si; }
        }
        __syncthreads();
        if (tid < 64) {
            float e = 0.f;
            if (tid < GPB) {
                float SR = redA[0][tid] + redA[1][tid] + redA[2][tid] + redA[3][tid];
                float SI = redB[0][tid] + redB[1][tid] + redB[2][tid] + redB[3][tid];
                e = skv[tid].w * (SR * SR + SI * SI);
            }
            e = wave_reduce(e);
            if (tid == 0) partial[slot] = e;
        }
    } else {
        // ========================== real space =============================
        // Branchless, straight-line body (single trip when KK==64): the 4
        // unrolled atoms expose 4 independent nm->pq[j] load chains that the
        // scheduler can overlap. Masked pairs read pq[0] safely (r2 forced 1).
        int rb = blk - CB;
        int t0 = rb * APB;
        int sys = t0 / N;                 // APB divides N -> block in one system
        const int Keff = KK ? KK : K;
        const float* C = cell + 9 * sys;
        float m0=C[0], m1=C[1], m2=C[2];
        float m3=C[3], m4=C[4], m5=C[5];
        float m6=C[6], m7=C[7], m8=C[8];

        float val = 0.0f;
        #pragma unroll
        for (int i = 0; i < APB/4; ++i) {
            int t = t0 + w * (APB/4) + i;
            float4 vi = pq[t];
            float xi = vi.x, yi = vi.y, zi = vi.z;
            float hqi = 0.5f * vi.w;
            if (lane == 0) val -= ALPHA * INV_SQRT_PI * vi.w * vi.w; // self term
            int nn = nnb[t];
            for (int k = lane; k < Keff; k += 64) {   // single trip when KK=64
                int p = t * Keff + k;
                int j = nm[p];
                int sx = shifts[3*p], sy = shifts[3*p+1], sz = shifts[3*p+2];
                bool msk = (j >= 0) && (k < nn);
                int js = j < 0 ? 0 : j;
                float4 vj = pq[js];
                float fx = (float)sx, fy = (float)sy, fz = (float)sz;
                float ox = fx*m0; ox = fmaf(fy, m3, ox); ox = fmaf(fz, m6, ox);
                float oy = fx*m1; oy = fmaf(fy, m4, oy); oy = fmaf(fz, m7, oy);
                float oz = fx*m2; oz = fmaf(fy, m5, oz); oz = fmaf(fz, m8, oz);
                float dx = vj.x + ox - xi;
                float dy = vj.y + oy - yi;
                float dz = vj.z + oz - zi;
                float r2 = fmaf(dx, dx, fmaf(dy, dy, dz*dz));
                r2 = msk ? r2 : 1.0f;                 // keep rsqrt finite
                float rinv = rsqrtf(r2);
                float d = r2 * rinv;
                float e = fast_erfc(ALPHA * d);
                float cq = msk ? hqi * vj.w : 0.f;
                val = fmaf(cq * rinv, e, val);
            }
        }

        val = wave_reduce(val);
        if (lane == 0) redr[w] = val;
        __syncthreads();
        if (tid == 0) {
            int rb_in_sys = rb - sys * (N / APB);
            partial[sys * STRIDE + rb_in_sys] =
                redr[0] + redr[1] + redr[2] + redr[3];
        }
    }
}

// -------- epilogue: per-system sum of partials, apply Coulomb constant -----
__global__ __launch_bounds__(256)
void final_reduce(const float* __restrict__ partial, float* __restrict__ out,
                  int nslots)
{
    __shared__ float red[4];
    const float COUL = 14.399645351950548f;
    int b = blockIdx.x;
    float v = 0.f;
    for (int s = threadIdx.x; s < nslots; s += 256)
        v += partial[b * STRIDE + s];
    v = wave_reduce(v);
    int lane = threadIdx.x & 63, w = threadIdx.x >> 6;
    if (lane == 0) red[w] = v;
    __syncthreads();
    if (threadIdx.x == 0)
        out[b] = COUL * (red[0] + red[1] + red[2] + red[3]);
}

// =================== legacy fallback (tiny workspace) ======================
__global__ __launch_bounds__(256)
void ewald_legacy(const float* __restrict__ pos, const float* __restrict__ chg,
                  const float* __restrict__ cell, const int* __restrict__ nm,
                  const int* __restrict__ shifts, const int* __restrict__ nnb,
                  float* __restrict__ partial, int T, int N, int K, int Bn, int CB)
{
    __shared__ float red[16];
    const float TWO_PI  = 6.283185307179586f;
    const float ALPHA   = 0.3f;
    const float INV4A2  = 2.7777777777f;
    const float KC2     = 1.0f;
    const float INV_SQRT_PI = 0.5641895835477563f;
    int blk = blockIdx.x;

    if (blk < CB) {
        int gpb_groups = (GTOT + GPB - 1) / GPB;
        int b   = blk / gpb_groups;
        int grp = blk % gpb_groups;
        const float* C = cell + 9 * b;
        float m00=C[0], m01=C[1], m02=C[2];
        float m10=C[3], m11=C[4], m12=C[5];
        float m20=C[6], m21=C[7], m22=C[8];
        float a00 = m11*m22 - m12*m21;
        float a01 = m02*m21 - m01*m22;
        float a02 = m01*m12 - m02*m11;
        float a10 = m12*m20 - m10*m22;
        float a11 = m00*m22 - m02*m20;
        float a12 = m02*m10 - m00*m12;
        float a20 = m10*m21 - m11*m20;
        float a21 = m01*m20 - m00*m21;
        float a22 = m00*m11 - m01*m10;
        float det = m00*a00 + m01*a10 + m02*a20;
        float invdet = 1.0f / det;
        float vol = fabsf(det);

        float kvx[GPB], kvy[GPB], kvz[GPB], coef[GPB];
        bool any = false;
        #pragma unroll
        for (int gi = 0; gi < GPB; ++gi) {
            int g = grp * GPB + gi;
            float cf = 0.f, kx = 0.f, ky = 0.f, kz = 0.f;
            if (g < GTOT) {
                int ix = g / 81, rem = g - ix * 81;
                int iy = rem / 9, iz = rem - iy * 9;
                int nx = ix - 4, ny = iy - 4, nz = iz - 4;
                bool pos_half = (nx > 0) || (nx == 0 && (ny > 0 || (ny == 0 && nz > 0)));
                if (pos_half) {
                    float fx = (float)nx, fy = (float)ny, fz = (float)nz;
                    kx = TWO_PI * invdet * (fx*a00 + fy*a01 + fz*a02);
                    ky = TWO_PI * invdet * (fx*a10 + fy*a11 + fz*a12);
                    kz = TWO_PI * invdet * (fx*a20 + fy*a21 + fz*a22);
                    float k2 = kx*kx + ky*ky + kz*kz;
                    if (k2 > 1e-10f && k2 <= KC2)
                        cf = 12.566370614359172f * __expf(-k2 * INV4A2) / (k2 * vol);
                }
            }
            kvx[gi] = kx; kvy[gi] = ky; kvz[gi] = kz; coef[gi] = cf;
            any = any || (cf != 0.f);
        }
        int slot = b * STRIDE + (N / APB) + grp;
        if (!any) { if (threadIdx.x == 0) partial[slot] = 0.f; return; }

        float Sre[GPB], Sim[GPB];
        #pragma unroll
        for (int gi = 0; gi < GPB; ++gi) { Sre[gi] = 0.f; Sim[gi] = 0.f; }
        for (int a = threadIdx.x; a < N; a += 256) {
            const float* pp = pos + (size_t)3 * (b * N + a);
            float x = pp[0], y = pp[1], z = pp[2];
            float qa = chg[(size_t)b * N + a];
            #pragma unroll
            for (int gi = 0; gi < GPB; ++gi) {
                if (coef[gi] != 0.f) {
                    float ph = x*kvx[gi] + y*kvy[gi] + z*kvz[gi];
                    float s, c;
                    __sincosf(ph, &s, &c);
                    Sre[gi] = fmaf(qa, c, Sre[gi]);
                    Sim[gi] = fmaf(qa, s, Sim[gi]);
                }
            }
        }
        int lane = threadIdx.x & 63, w = threadIdx.x >> 6;
        float e_acc = 0.f;
        #pragma unroll
        for (int gi = 0; gi < GPB; ++gi) {
            if (coef[gi] != 0.f) {
                float sr = wave_reduce(Sre[gi]);
                float si = wave_reduce(Sim[gi]);
                if (lane == 0) { red[2*w] = sr; red[2*w+1] = si; }
                __syncthreads();
                if (threadIdx.x == 0) {
                    float SR = red[0] + red[2] + red[4] + red[6];
                    float SI = red[1] + red[3] + red[5] + red[7];
                    e_acc += coef[gi] * (SR*SR + SI*SI);
                }
                __syncthreads();
            }
        }
        if (threadIdx.x == 0) partial[slot] = e_acc;
    } else {
        int rb = blk - CB;
        int t0 = rb * APB;
        int sys = t0 / N;
        int lane = threadIdx.x & 63, w = threadIdx.x >> 6;
        float val = 0.0f;
        #pragma unroll
        for (int i = 0; i < APB/4; ++i) {
            int t = t0 + w * (APB/4) + i;
            float xi = pos[3*t], yi = pos[3*t+1], zi = pos[3*t+2];
            float qi = chg[t];
            if (lane == 0) val -= ALPHA * INV_SQRT_PI * qi * qi;
            int nn = nnb[t];
            for (int k = lane; k < K; k += 64) {
                int p = t * K + k;
                int j = nm[p];
                bool msk = (j >= 0) && (k < nn);
                if (msk) {
                    int sx = shifts[3*p], sy = shifts[3*p+1], sz = shifts[3*p+2];
                    float ox = 0.f, oy = 0.f, oz = 0.f;
                    if ((sx | sy | sz) != 0) {
                        const float* C = cell + 9 * sys;
                        float fx = (float)sx, fy = (float)sy, fz = (float)sz;
                        ox = fx*C[0] + fy*C[3] + fz*C[6];
                        oy = fx*C[1] + fy*C[4] + fz*C[7];
                        oz = fx*C[2] + fy*C[5] + fz*C[8];
                    }
                    float dx = pos[3*j] + ox - xi;
                    float dy = pos[3*j+1] + oy - yi;
                    float dz = pos[3*j+2] + oz - zi;
                    float r2 = fmaf(dx, dx, fmaf(dy, dy, dz*dz));
                    float rinv = rsqrtf(r2);
                    float d = r2 * rinv;
                    val += 0.5f * qi * chg[j] * fast_erfc(ALPHA * d) * rinv;
                }
            }
        }
        val = wave_reduce(val);
        if (lane == 0) red[w] = val;
        __syncthreads();
        if (threadIdx.x == 0) {
            int rb_in_sys = rb - sys * (N / APB);
            partial[sys * STRIDE + rb_in_sys] = red[0] + red[1] + red[2] + red[3];
        }
    }
}

extern "C" void kernel_launch(void* const* d_in, const int* in_sizes, int n_in,
                              void* d_out, int out_size, void* d_ws, size_t ws_size,
                              hipStream_t stream) {
    const float* pos    = (const float*)d_in[0];
    const float* chg    = (const float*)d_in[1];
    const float* cellp  = (const float*)d_in[2];
    const int*   nm     = (const int*)d_in[3];
    const int*   shifts = (const int*)d_in[4];
    const int*   nnb    = (const int*)d_in[5];

    int T  = in_sizes[1];          // 64000
    int Bn = in_sizes[2] / 9;      // 16
    int N  = T / Bn;               // 4000
    int K  = in_sizes[3] / T;      // 64

    // workspace layout: partial | pq (float4) | kcomp (float4) | kcnt
    size_t partBytes = (size_t)Bn * STRIDE * sizeof(float);
    size_t pqOff     = ((partBytes + 255) / 256) * 256;
    size_t pqBytes   = (size_t)T * sizeof(float4);
    size_t kOff      = ((pqOff + pqBytes + 255) / 256) * 256;
    size_t kBytes    = (size_t)Bn * KMAX * sizeof(float4);
    size_t cntOff    = kOff + kBytes;
    size_t needed    = cntOff + (size_t)Bn * sizeof(int);

    if ((N % APB) == 0 && ws_size >= needed) {
        float*  partial = (float*)d_ws;
        float4* pq      = (float4*)((char*)d_ws + pqOff);
        float4* kcomp   = (float4*)((char*)d_ws + kOff);
        int*    kcnt    = (int*)((char*)d_ws + cntOff);

        int PB = (T + 255) / 256;              // 250 pack blocks
        int CB = Bn * GMAX;                    // 736 recip blocks (some early-exit)
        int RB = T / APB;                      // 4000 real blocks
        int nslots = (N / APB) + GMAX;         // 296

        prologue<<<PB + Bn, 256, 0, stream>>>(pos, chg, pq, cellp, kcomp, kcnt,
                                              T, PB);
        if (K == 64)
            ewald_fused2<64><<<CB + RB, 256, 0, stream>>>(
                pq, cellp, nm, shifts, nnb, kcomp, kcnt, partial, T, N, K, Bn, CB);
        else
            ewald_fused2<0><<<CB + RB, 256, 0, stream>>>(
                pq, cellp, nm, shifts, nnb, kcomp, kcnt, partial, T, N, K, Bn, CB);
        final_reduce<<<Bn, 256, 0, stream>>>(partial, (float*)d_out, nslots);
    } else {
        // legacy path: no packing, no compaction, 2 kernels, tiny workspace
        float* partial = (float*)d_ws;
        int CB = Bn * ((GTOT + GPB - 1) / GPB);
        int RB = T / APB;
        int nslots = (N / APB) + ((GTOT + GPB - 1) / GPB);
        ewald_legacy<<<CB + RB, 256, 0, stream>>>(pos, chg, cellp, nm, shifts,
                                                  nnb, partial, T, N, K, Bn, CB);
        final_reduce<<<Bn, 256, 0, stream>>>(partial, (float*)d_out, nslots);
    }
}

// Round 8
// 119.983 us; speedup vs baseline: 1.6569x; 1.0005x over previous
//
#include <hip/hip_runtime.h>
#include <math.h>

// Problem constants (match reference config)
#define GPB    8                 // k-vectors per reciprocal block
#define GTOT   729               // (2*NMAX+1)^3, NMAX=4
#define GMAX   46                // ceil(364/8): worst-case active half-sphere k's / GPB
#define KMAX   (GMAX*GPB)        // compacted k slots per system (padded)
#define APB    8                 // atoms per real block (128 thr = 2 waves x 4 atoms)
#define LAPB   16                // atoms per real block in legacy fallback (256 thr)
#define STRIDE 600               // partial slots per system: 500 real + 46 recip (+legacy 250+92)

__device__ __forceinline__ float wave_reduce(float v) {
    #pragma unroll
    for (int off = 32; off > 0; off >>= 1) v += __shfl_down(v, off, 64);
    return v;
}

// Abramowitz & Stegun 7.1.26: erfc(x) for x>=0, |abs err| <= 1.5e-7.
__device__ __forceinline__ float fast_erfc(float x) {
    float t = __builtin_amdgcn_rcpf(fmaf(0.3275911f, x, 1.0f));
    float p = fmaf(1.061405429f, t, -1.453152027f);
    p = fmaf(p, t, 1.421413741f);
    p = fmaf(p, t, -0.284496736f);
    p = fmaf(p, t, 0.254829592f);
    return p * t * __expf(-x * x);
}

// ---------- prologue: pack pq (PB blocks) + compact k-vectors (Bn blocks) ---
// NOTE: recip energy is quadratic in S(k) -> the FULL atom sum must stay in
// one block per (system, k-group). Do NOT slice the atom loop (round-4 bug).
__global__ __launch_bounds__(256)
void prologue(const float* __restrict__ pos, const float* __restrict__ chg,
              float4* __restrict__ pq, const float* __restrict__ cell,
              float4* __restrict__ kcomp, int* __restrict__ kcnt,
              int T, int PB)
{
    int blk = blockIdx.x;
    if (blk < PB) {
        int t = blk * 256 + threadIdx.x;
        if (t < T)
            pq[t] = make_float4(pos[3*t], pos[3*t+1], pos[3*t+2], chg[t]);
        return;
    }
    // one system per block; wave 0 does the compaction scan
    int b = blk - PB;
    if (threadIdx.x >= 64) return;

    const float TWO_PI = 6.283185307179586f;
    const float INV4A2 = 2.7777777777f;          // 1/(4*ALPHA^2)
    const float KC2    = 1.0f;
    int lane = threadIdx.x;

    const float* C = cell + 9 * b;
    float m00=C[0], m01=C[1], m02=C[2];
    float m10=C[3], m11=C[4], m12=C[5];
    float m20=C[6], m21=C[7], m22=C[8];
    float a00 = m11*m22 - m12*m21;
    float a01 = m02*m21 - m01*m22;
    float a02 = m01*m12 - m02*m11;
    float a10 = m12*m20 - m10*m22;
    float a11 = m00*m22 - m02*m20;
    float a12 = m02*m10 - m00*m12;
    float a20 = m10*m21 - m11*m20;
    float a21 = m01*m20 - m00*m21;
    float a22 = m00*m11 - m01*m10;
    float det = m00*a00 + m01*a10 + m02*a20;
    float invdet = 1.0f / det;
    float vol = fabsf(det);

    int cnt = 0;
    for (int base = 0; base < GTOT; base += 64) {
        int g = base + lane;
        float kx = 0.f, ky = 0.f, kz = 0.f, cf = 0.f;
        if (g < GTOT) {
            int ix = g / 81, rem = g - ix * 81;
            int iy = rem / 9, iz = rem - iy * 9;
            int nx = ix - 4, ny = iy - 4, nz = iz - 4;
            // half-sphere: keep lexicographically-positive n, double coef
            bool pos_half = (nx > 0) || (nx == 0 && (ny > 0 || (ny == 0 && nz > 0)));
            if (pos_half) {
                float fx = (float)nx, fy = (float)ny, fz = (float)nz;
                kx = TWO_PI * invdet * (fx*a00 + fy*a01 + fz*a02);
                ky = TWO_PI * invdet * (fx*a10 + fy*a11 + fz*a12);
                kz = TWO_PI * invdet * (fx*a20 + fy*a21 + fz*a22);
                float k2 = kx*kx + ky*ky + kz*kz;
                if (k2 > 1e-10f && k2 <= KC2) {
                    // 2 * [4*pi*exp(-k2/4a^2)/k2] / (2*vol)  (half-sphere doubling)
                    cf = 12.566370614359172f * __expf(-k2 * INV4A2) / (k2 * vol);
                }
            }
        }
        bool act = (cf != 0.f);
        unsigned long long m = __ballot(act);
        if (act) {
            int off = __popcll(m & ((1ull << lane) - 1ull));
            kcomp[b * KMAX + cnt + off] = make_float4(kx, ky, kz, cf);
        }
        cnt += (int)__popcll(m);
    }
    // pad to a multiple of GPB with dead entries so groups unroll densely
    int padded = ((cnt + GPB - 1) / GPB) * GPB;
    if (lane < padded - cnt)
        kcomp[b * KMAX + cnt + lane] = make_float4(0.f, 0.f, 0.f, 0.f);
    if (lane == 0) kcnt[b] = padded / GPB;
}

// ---------- fused main kernel, 128-thread blocks (2 waves) ------------------
// KK = compile-time K (0 -> runtime loop). 128-thr blocks double per-CU
// workgroup residency vs 256 -> more loads in flight (TLP) for the
// latency-bound neighbor streams.
template <int KK>
__global__ __launch_bounds__(128)
void ewald_fused2(const float4* __restrict__ pq,    // packed [T]
                  const float*  __restrict__ cell,  // [Bn,3,3]
                  const int*    __restrict__ nm,    // [T,K]
                  const int*    __restrict__ shifts,// [T,K,3]
                  const int*    __restrict__ nnb,   // [T]
                  const float4* __restrict__ kcomp, // [Bn,KMAX]
                  const int*    __restrict__ kcnt,  // [Bn]
                  float* __restrict__ partial,      // [Bn][STRIDE]
                  int T, int N, int K, int Bn, int CB)
{
    __shared__ float4 skv[GPB];
    __shared__ float  redA[2][GPB];
    __shared__ float  redB[2][GPB];
    __shared__ float  redr[2];

    const float ALPHA       = 0.3f;
    const float INV_SQRT_PI = 0.5641895835477563f;

    int blk  = blockIdx.x;
    int tid  = threadIdx.x;
    int lane = tid & 63;
    int w    = tid >> 6;                       // 0 or 1

    if (blk < CB) {
        // ======================= reciprocal space ==========================
        int b    = blk / GMAX;
        int grp  = blk - b * GMAX;
        int slot = b * STRIDE + (N / APB) + grp;
        int ng   = kcnt[b];
        if (grp >= ng) {                           // dead block: no atom loop
            if (tid == 0) partial[slot] = 0.f;
            return;
        }

        if (tid < GPB)
            skv[tid] = kcomp[b * KMAX + grp * GPB + tid];
        __syncthreads();

        float kvx[GPB], kvy[GPB], kvz[GPB];
        #pragma unroll
        for (int gi = 0; gi < GPB; ++gi) {
            float4 v = skv[gi];
            kvx[gi] = v.x; kvy[gi] = v.y; kvz[gi] = v.z;
        }

        float Sre[GPB], Sim[GPB];
        #pragma unroll
        for (int gi = 0; gi < GPB; ++gi) { Sre[gi] = 0.f; Sim[gi] = 0.f; }

        // dense inner loop over ALL N atoms, 2 atoms per iteration (128 thr)
        const float4* pb = pq + (size_t)b * N;
        int a = tid;
        for (; a + 128 < N; a += 256) {
            float4 v0 = pb[a];
            float4 v1 = pb[a + 128];
            #pragma unroll
            for (int gi = 0; gi < GPB; ++gi) {
                float ph0 = fmaf(v0.x, kvx[gi], fmaf(v0.y, kvy[gi], v0.z * kvz[gi]));
                float ph1 = fmaf(v1.x, kvx[gi], fmaf(v1.y, kvy[gi], v1.z * kvz[gi]));
                float s0, c0, s1, c1;
                __sincosf(ph0, &s0, &c0);
                __sincosf(ph1, &s1, &c1);
                Sre[gi] = fmaf(v0.w, c0, Sre[gi]);
                Sim[gi] = fmaf(v0.w, s0, Sim[gi]);
                Sre[gi] = fmaf(v1.w, c1, Sre[gi]);
                Sim[gi] = fmaf(v1.w, s1, Sim[gi]);
            }
        }
        if (a < N) {                               // tail atom
            float4 v0 = pb[a];
            #pragma unroll
            for (int gi = 0; gi < GPB; ++gi) {
                float ph0 = fmaf(v0.x, kvx[gi], fmaf(v0.y, kvy[gi], v0.z * kvz[gi]));
                float s0, c0;
                __sincosf(ph0, &s0, &c0);
                Sre[gi] = fmaf(v0.w, c0, Sre[gi]);
                Sim[gi] = fmaf(v0.w, s0, Sim[gi]);
            }
        }

        // single-sync reduction: wave partials -> LDS -> wave 0 finishes
        #pragma unroll
        for (int gi = 0; gi < GPB; ++gi) {
            float sr = wave_reduce(Sre[gi]);
            float si = wave_reduce(Sim[gi]);
            if (lane == 0) { redA[w][gi] = sr; redB[w][gi] = si; }
        }
        __syncthreads();
        if (tid < 64) {
            float e = 0.f;
            if (tid < GPB) {
                float SR = redA[0][tid] + redA[1][tid];
                float SI = redB[0][tid] + redB[1][tid];
                e = skv[tid].w * (SR * SR + SI * SI);
            }
            e = wave_reduce(e);
            if (tid == 0) partial[slot] = e;
        }
    } else {
        // ========================== real space =============================
        // Branchless straight-line body (single trip when KK==64): the 4
        // unrolled atoms per thread expose 4 independent nm->pq[j] chains.
        int rb = blk - CB;
        int t0 = rb * APB;
        int sys = t0 / N;                 // APB divides N -> block in one system
        const int Keff = KK ? KK : K;
        const float* C = cell + 9 * sys;
        float m0=C[0], m1=C[1], m2=C[2];
        float m3=C[3], m4=C[4], m5=C[5];
        float m6=C[6], m7=C[7], m8=C[8];

        float val = 0.0f;
        #pragma unroll
        for (int i = 0; i < APB/2; ++i) {          // 2 waves x 4 atoms
            int t = t0 + w * (APB/2) + i;
            float4 vi = pq[t];
            float xi = vi.x, yi = vi.y, zi = vi.z;
            float hqi = 0.5f * vi.w;
            if (lane == 0) val -= ALPHA * INV_SQRT_PI * vi.w * vi.w; // self term
            int nn = nnb[t];
            for (int k = lane; k < Keff; k += 64) {   // single trip when KK=64
                int p = t * Keff + k;
                int j = nm[p];
                int sx = shifts[3*p], sy = shifts[3*p+1], sz = shifts[3*p+2];
                bool msk = (j >= 0) && (k < nn);
                int js = j < 0 ? 0 : j;
                float4 vj = pq[js];
                float fx = (float)sx, fy = (float)sy, fz = (float)sz;
                float ox = fx*m0; ox = fmaf(fy, m3, ox); ox = fmaf(fz, m6, ox);
                float oy = fx*m1; oy = fmaf(fy, m4, oy); oy = fmaf(fz, m7, oy);
                float oz = fx*m2; oz = fmaf(fy, m5, oz); oz = fmaf(fz, m8, oz);
                float dx = vj.x + ox - xi;
                float dy = vj.y + oy - yi;
                float dz = vj.z + oz - zi;
                float r2 = fmaf(dx, dx, fmaf(dy, dy, dz*dz));
                r2 = msk ? r2 : 1.0f;                 // keep rsqrt finite
                float rinv = rsqrtf(r2);
                float d = r2 * rinv;
                float e = fast_erfc(ALPHA * d);
                float cq = msk ? hqi * vj.w : 0.f;
                val = fmaf(cq * rinv, e, val);
            }
        }

        val = wave_reduce(val);
        if (lane == 0) redr[w] = val;
        __syncthreads();
        if (tid == 0) {
            int rb_in_sys = rb - sys * (N / APB);
            partial[sys * STRIDE + rb_in_sys] = redr[0] + redr[1];
        }
    }
}

// -------- epilogue: per-system sum of partials, apply Coulomb constant -----
__global__ __launch_bounds__(256)
void final_reduce(const float* __restrict__ partial, float* __restrict__ out,
                  int nslots)
{
    __shared__ float red[4];
    const float COUL = 14.399645351950548f;
    int b = blockIdx.x;
    float v = 0.f;
    for (int s = threadIdx.x; s < nslots; s += 256)
        v += partial[b * STRIDE + s];
    v = wave_reduce(v);
    int lane = threadIdx.x & 63, w = threadIdx.x >> 6;
    if (lane == 0) red[w] = v;
    __syncthreads();
    if (threadIdx.x == 0)
        out[b] = COUL * (red[0] + red[1] + red[2] + red[3]);
}

// =================== legacy fallback (tiny workspace, 256 thr) =============
__global__ __launch_bounds__(256)
void ewald_legacy(const float* __restrict__ pos, const float* __restrict__ chg,
                  const float* __restrict__ cell, const int* __restrict__ nm,
                  const int* __restrict__ shifts, const int* __restrict__ nnb,
                  float* __restrict__ partial, int T, int N, int K, int Bn, int CB)
{
    __shared__ float red[16];
    const float TWO_PI  = 6.283185307179586f;
    const float ALPHA   = 0.3f;
    const float INV4A2  = 2.7777777777f;
    const float KC2     = 1.0f;
    const float INV_SQRT_PI = 0.5641895835477563f;
    int blk = blockIdx.x;

    if (blk < CB) {
        int gpb_groups = (GTOT + GPB - 1) / GPB;
        int b   = blk / gpb_groups;
        int grp = blk % gpb_groups;
        const float* C = cell + 9 * b;
        float m00=C[0], m01=C[1], m02=C[2];
        float m10=C[3], m11=C[4], m12=C[5];
        float m20=C[6], m21=C[7], m22=C[8];
        float a00 = m11*m22 - m12*m21;
        float a01 = m02*m21 - m01*m22;
        float a02 = m01*m12 - m02*m11;
        float a10 = m12*m20 - m10*m22;
        float a11 = m00*m22 - m02*m20;
        float a12 = m02*m10 - m00*m12;
        float a20 = m10*m21 - m11*m20;
        float a21 = m01*m20 - m00*m21;
        float a22 = m00*m11 - m01*m10;
        float det = m00*a00 + m01*a10 + m02*a20;
        float invdet = 1.0f / det;
        float vol = fabsf(det);

        float kvx[GPB], kvy[GPB], kvz[GPB], coef[GPB];
        bool any = false;
        #pragma unroll
        for (int gi = 0; gi < GPB; ++gi) {
            int g = grp * GPB + gi;
            float cf = 0.f, kx = 0.f, ky = 0.f, kz = 0.f;
            if (g < GTOT) {
                int ix = g / 81, rem = g - ix * 81;
                int iy = rem / 9, iz = rem - iy * 9;
                int nx = ix - 4, ny = iy - 4, nz = iz - 4;
                bool pos_half = (nx > 0) || (nx == 0 && (ny > 0 || (ny == 0 && nz > 0)));
                if (pos_half) {
                    float fx = (float)nx, fy = (float)ny, fz = (float)nz;
                    kx = TWO_PI * invdet * (fx*a00 + fy*a01 + fz*a02);
                    ky = TWO_PI * invdet * (fx*a10 + fy*a11 + fz*a12);
                    kz = TWO_PI * invdet * (fx*a20 + fy*a21 + fz*a22);
                    float k2 = kx*kx + ky*ky + kz*kz;
                    if (k2 > 1e-10f && k2 <= KC2)
                        cf = 12.566370614359172f * __expf(-k2 * INV4A2) / (k2 * vol);
                }
            }
            kvx[gi] = kx; kvy[gi] = ky; kvz[gi] = kz; coef[gi] = cf;
            any = any || (cf != 0.f);
        }
        int slot = b * STRIDE + (N / LAPB) + grp;
        if (!any) { if (threadIdx.x == 0) partial[slot] = 0.f; return; }

        float Sre[GPB], Sim[GPB];
        #pragma unroll
        for (int gi = 0; gi < GPB; ++gi) { Sre[gi] = 0.f; Sim[gi] = 0.f; }
        for (int a = threadIdx.x; a < N; a += 256) {
            const float* pp = pos + (size_t)3 * (b * N + a);
            float x = pp[0], y = pp[1], z = pp[2];
            float qa = chg[(size_t)b * N + a];
            #pragma unroll
            for (int gi = 0; gi < GPB; ++gi) {
                if (coef[gi] != 0.f) {
                    float ph = x*kvx[gi] + y*kvy[gi] + z*kvz[gi];
                    float s, c;
                    __sincosf(ph, &s, &c);
                    Sre[gi] = fmaf(qa, c, Sre[gi]);
                    Sim[gi] = fmaf(qa, s, Sim[gi]);
                }
            }
        }
        int lane = threadIdx.x & 63, w = threadIdx.x >> 6;
        float e_acc = 0.f;
        #pragma unroll
        for (int gi = 0; gi < GPB; ++gi) {
            if (coef[gi] != 0.f) {
                float sr = wave_reduce(Sre[gi]);
                float si = wave_reduce(Sim[gi]);
                if (lane == 0) { red[2*w] = sr; red[2*w+1] = si; }
                __syncthreads();
                if (threadIdx.x == 0) {
                    float SR = red[0] + red[2] + red[4] + red[6];
                    float SI = red[1] + red[3] + red[5] + red[7];
                    e_acc += coef[gi] * (SR*SR + SI*SI);
                }
                __syncthreads();
            }
        }
        if (threadIdx.x == 0) partial[slot] = e_acc;
    } else {
        int rb = blk - CB;
        int t0 = rb * LAPB;
        int sys = t0 / N;
        int lane = threadIdx.x & 63, w = threadIdx.x >> 6;
        float val = 0.0f;
        #pragma unroll
        for (int i = 0; i < LAPB/4; ++i) {
            int t = t0 + w * (LAPB/4) + i;
            float xi = pos[3*t], yi = pos[3*t+1], zi = pos[3*t+2];
            float qi = chg[t];
            if (lane == 0) val -= ALPHA * INV_SQRT_PI * qi * qi;
            int nn = nnb[t];
            for (int k = lane; k < K; k += 64) {
                int p = t * K + k;
                int j = nm[p];
                bool msk = (j >= 0) && (k < nn);
                if (msk) {
                    int sx = shifts[3*p], sy = shifts[3*p+1], sz = shifts[3*p+2];
                    float ox = 0.f, oy = 0.f, oz = 0.f;
                    if ((sx | sy | sz) != 0) {
                        const float* C = cell + 9 * sys;
                        float fx = (float)sx, fy = (float)sy, fz = (float)sz;
                        ox = fx*C[0] + fy*C[3] + fz*C[6];
                        oy = fx*C[1] + fy*C[4] + fz*C[7];
                        oz = fx*C[2] + fy*C[5] + fz*C[8];
                    }
                    float dx = pos[3*j] + ox - xi;
                    float dy = pos[3*j+1] + oy - yi;
                    float dz = pos[3*j+2] + oz - zi;
                    float r2 = fmaf(dx, dx, fmaf(dy, dy, dz*dz));
                    float rinv = rsqrtf(r2);
                    float d = r2 * rinv;
                    val += 0.5f * qi * chg[j] * fast_erfc(ALPHA * d) * rinv;
                }
            }
        }
        val = wave_reduce(val);
        if (lane == 0) red[w] = val;
        __syncthreads();
        if (threadIdx.x == 0) {
            int rb_in_sys = rb - sys * (N / LAPB);
            partial[sys * STRIDE + rb_in_sys] = red[0] + red[1] + red[2] + red[3];
        }
    }
}

extern "C" void kernel_launch(void* const* d_in, const int* in_sizes, int n_in,
                              void* d_out, int out_size, void* d_ws, size_t ws_size,
                              hipStream_t stream) {
    const float* pos    = (const float*)d_in[0];
    const float* chg    = (const float*)d_in[1];
    const float* cellp  = (const float*)d_in[2];
    const int*   nm     = (const int*)d_in[3];
    const int*   shifts = (const int*)d_in[4];
    const int*   nnb    = (const int*)d_in[5];

    int T  = in_sizes[1];          // 64000
    int Bn = in_sizes[2] / 9;      // 16
    int N  = T / Bn;               // 4000
    int K  = in_sizes[3] / T;      // 64

    // workspace layout: partial | pq (float4) | kcomp (float4) | kcnt
    size_t partBytes = (size_t)Bn * STRIDE * sizeof(float);
    size_t pqOff     = ((partBytes + 255) / 256) * 256;
    size_t pqBytes   = (size_t)T * sizeof(float4);
    size_t kOff      = ((pqOff + pqBytes + 255) / 256) * 256;
    size_t kBytes    = (size_t)Bn * KMAX * sizeof(float4);
    size_t cntOff    = kOff + kBytes;
    size_t needed    = cntOff + (size_t)Bn * sizeof(int);

    if ((N % APB) == 0 && ws_size >= needed) {
        float*  partial = (float*)d_ws;
        float4* pq      = (float4*)((char*)d_ws + pqOff);
        float4* kcomp   = (float4*)((char*)d_ws + kOff);
        int*    kcnt    = (int*)((char*)d_ws + cntOff);

        int PB = (T + 255) / 256;              // 250 pack blocks
        int CB = Bn * GMAX;                    // 736 recip blocks (some early-exit)
        int RB = T / APB;                      // 8000 real blocks
        int nslots = (N / APB) + GMAX;         // 546

        prologue<<<PB + Bn, 256, 0, stream>>>(pos, chg, pq, cellp, kcomp, kcnt,
                                              T, PB);
        if (K == 64)
            ewald_fused2<64><<<CB + RB, 128, 0, stream>>>(
                pq, cellp, nm, shifts, nnb, kcomp, kcnt, partial, T, N, K, Bn, CB);
        else
            ewald_fused2<0><<<CB + RB, 128, 0, stream>>>(
                pq, cellp, nm, shifts, nnb, kcomp, kcnt, partial, T, N, K, Bn, CB);
        final_reduce<<<Bn, 256, 0, stream>>>(partial, (float*)d_out, nslots);
    } else {
        // legacy path: no packing, no compaction, 2 kernels, tiny workspace
        float* partial = (float*)d_ws;
        int CB = Bn * ((GTOT + GPB - 1) / GPB);
        int RB = T / LAPB;
        int nslots = (N / LAPB) + ((GTOT + GPB - 1) / GPB);
        ewald_legacy<<<CB + RB, 256, 0, stream>>>(pos, chg, cellp, nm, shifts,
                                                  nnb, partial, T, N, K, Bn, CB);
        final_reduce<<<Bn, 256, 0, stream>>>(partial, (float*)d_out, nslots);
    }
}